// Round 4
// baseline (681.088 us; speedup 1.0000x reference)
//
#include <hip/hip_runtime.h>
#include <stdint.h>

// B=128, H=1024, L=64, V=32000
typedef __attribute__((ext_vector_type(8))) short short8_t;
typedef __attribute__((ext_vector_type(4))) float floatx4;

__device__ __forceinline__ unsigned short f32_to_bf16_rne(float f) {
  unsigned int u = __float_as_uint(f);
  u += 0x7fffu + ((u >> 16) & 1u);
  return (unsigned short)(u >> 16);
}
__device__ __forceinline__ float bf16_to_f32(unsigned short h) {
  return __uint_as_float(((unsigned int)h) << 16);
}

// async global->LDS, 16B per lane; LDS dest is wave-uniform base + lane*16
#define GLL16(gp, lp) __builtin_amdgcn_global_load_lds(               \
    (__attribute__((address_space(1))) void*)(gp),                    \
    (__attribute__((address_space(3))) void*)(lp), 16, 0, 0)

// ---------------------------------------------------------------------------
// K1: bf16 conversions + embedding gather.
// enc [128*64*2048] -> enc_b ; Ua [1024*2048] -> Ua_b ;
// h0 -> xcat[:,3072:4096] ; emb[ids] -> xcat[:,0:1024]
__global__ void k_prep(const float* __restrict__ enc, const float* __restrict__ Ua,
                       const float* __restrict__ h0, const float* __restrict__ emb,
                       const int* __restrict__ ids,
                       unsigned short* __restrict__ enc_b,
                       unsigned short* __restrict__ Ua_b,
                       unsigned short* __restrict__ xcat) {
  const int ENC4 = 4194304, UA4 = 524288, H04 = 32768, EMB4 = 32768;
  const int total = ENC4 + UA4 + H04 + EMB4;
  for (int i = blockIdx.x * blockDim.x + threadIdx.x; i < total;
       i += gridDim.x * blockDim.x) {
    float4 v;
    ushort4* dst;
    if (i < ENC4) {
      v = ((const float4*)enc)[i];
      dst = ((ushort4*)enc_b) + i;
    } else if (i < ENC4 + UA4) {
      int j = i - ENC4;
      v = ((const float4*)Ua)[j];
      dst = ((ushort4*)Ua_b) + j;
    } else if (i < ENC4 + UA4 + H04) {
      int j = i - ENC4 - UA4;
      int b = j >> 8, k4 = j & 255;         // 256 float4 per row of 1024
      v = ((const float4*)h0)[j];
      dst = ((ushort4*)xcat) + (b * 1024 + 768 + k4);  // ushort4 ld = 1024
    } else {
      int j = i - ENC4 - UA4 - H04;
      int b = j >> 8, k4 = j & 255;
      v = ((const float4*)(emb + (size_t)ids[b] * 1024))[k4];
      dst = ((ushort4*)xcat) + (b * 1024 + k4);
    }
    ushort4 o;
    o.x = f32_to_bf16_rne(v.x); o.y = f32_to_bf16_rne(v.y);
    o.z = f32_to_bf16_rne(v.z); o.w = f32_to_bf16_rne(v.w);
    *dst = o;
  }
}

// ---------------------------------------------------------------------------
// K3: ua_e = enc_b @ Ua_b^T  -> bf16 [8192][1024]
// m97-style: BM=BN=128, BK=32, 256 thr (4 waves, 2x2 of 64x64), global_load_lds.
__global__ __launch_bounds__(256, 2) void k_gemm_uae(
    const unsigned short* __restrict__ A,   // [8192][2048] bf16
    const unsigned short* __restrict__ Bw,  // [1024][2048] bf16
    unsigned short* __restrict__ C) {       // [8192][1024] bf16
  const int K = 2048;
  __shared__ __align__(16) unsigned short As[128 * 32];
  __shared__ __align__(16) unsigned short Bs[128 * 32];
  const int tid = threadIdx.x;
  const int wave = tid >> 6, lane = tid & 63;
  const int m0 = blockIdx.y * 128, n0 = blockIdx.x * 128;
  const int wm = (wave >> 1) * 64, wn = (wave & 1) * 64;
  const int lr = lane & 15, lk = lane >> 4;
  floatx4 acc[4][4] = {};
  for (int kt = 0; kt < K; kt += 32) {
    __syncthreads();
#pragma unroll
    for (int q = 0; q < 2; ++q) {
      int s = wave * 128 + q * 64 + lane;   // slot: row=s>>2 (0..127), kc=s&3
      const unsigned short* ga = A + (size_t)(m0 + (s >> 2)) * K + kt + (s & 3) * 8;
      GLL16(ga, ((char*)As) + (wave * 128 + q * 64) * 16);
      const unsigned short* gb = Bw + (size_t)(n0 + (s >> 2)) * K + kt + (s & 3) * 8;
      GLL16(gb, ((char*)Bs) + (wave * 128 + q * 64) * 16);
    }
    __syncthreads();
    short8_t af[4], bf[4];
#pragma unroll
    for (int i = 0; i < 4; ++i) {
      af[i] = *(const short8_t*)((const char*)As + (wm + i * 16 + lr) * 64 + lk * 16);
      bf[i] = *(const short8_t*)((const char*)Bs + (wn + i * 16 + lr) * 64 + lk * 16);
    }
#pragma unroll
    for (int i = 0; i < 4; ++i)
#pragma unroll
      for (int j = 0; j < 4; ++j)
        acc[i][j] = __builtin_amdgcn_mfma_f32_16x16x32_bf16(af[i], bf[j], acc[i][j], 0, 0, 0);
  }
  // C/D layout: col = lane&15, row = (lane>>4)*4 + r   [m89/m91 verified]
#pragma unroll
  for (int i = 0; i < 4; ++i)
#pragma unroll
    for (int j = 0; j < 4; ++j)
#pragma unroll
      for (int r = 0; r < 4; ++r) {
        int row = m0 + wm + i * 16 + (lane >> 4) * 4 + r;
        int col = n0 + wn + j * 16 + lr;
        C[(size_t)row * 1024 + col] = f32_to_bf16_rne(acc[i][j][r]);
      }
}

// ---------------------------------------------------------------------------
// Small-M (M=128) BT-GEMM: C[128][N] f32 = A_bf16[128][K] @ W_f32[N][K]^T
// A staged in LDS; W loaded f32 -> cvt bf16 -> B-frag directly (each W elem
// used once; memory-bound). Optional 2-region W (gates), optional K-split via
// blockIdx.y into separate partial slabs, optional 2 biases.
__global__ void k_gemm_smallM(const unsigned short* __restrict__ A, int lda,
                              const float* __restrict__ W1, int ldw1, int k1,
                              const float* __restrict__ W2, int ldw2,
                              const float* __restrict__ bias1,
                              const float* __restrict__ bias2,
                              float* __restrict__ Cout, int ldc,
                              int Ktot, int kchunk) {
  __shared__ __align__(16) unsigned short As[128 * 32];  // 8KB
  const int tid = threadIdx.x, wave = tid >> 6, lane = tid & 63;
  const int n0 = blockIdx.x * 64 + wave * 16;
  const int lr = lane & 15, lk = lane >> 4;
  const int kbeg = blockIdx.y * kchunk;
  const int kend = (kbeg + kchunk < Ktot) ? kbeg + kchunk : Ktot;
  float* outp = Cout + (size_t)blockIdx.y * 128 * ldc;
  floatx4 acc[8] = {};
  for (int kt = kbeg; kt < kend; kt += 32) {
    __syncthreads();
#pragma unroll
    for (int q = 0; q < 2; ++q) {
      int s = wave * 128 + q * 64 + lane;
      const unsigned short* ga = A + (size_t)(s >> 2) * lda + kt + (s & 3) * 8;
      GLL16(ga, ((char*)As) + (wave * 128 + q * 64) * 16);
    }
    __syncthreads();
    // B fragment: lane holds W[n0+lr][kt + lk*8 .. +7]
    int wr = n0 + lr;
    int kk = kt + lk * 8;
    const float* wp;
    if (kk < k1) wp = W1 + (size_t)wr * ldw1 + kk;
    else         wp = W2 + (size_t)wr * ldw2 + (kk - k1);
    floatx4 w0 = *(const floatx4*)(wp);
    floatx4 w1 = *(const floatx4*)(wp + 4);
    short8_t bf;
#pragma unroll
    for (int j = 0; j < 4; ++j) {
      bf[j]     = (short)f32_to_bf16_rne(w0[j]);
      bf[4 + j] = (short)f32_to_bf16_rne(w1[j]);
    }
#pragma unroll
    for (int am = 0; am < 8; ++am) {
      short8_t af = *(const short8_t*)((const char*)As + (am * 16 + lr) * 64 + lk * 16);
      acc[am] = __builtin_amdgcn_mfma_f32_16x16x32_bf16(af, bf, acc[am], 0, 0, 0);
    }
  }
#pragma unroll
  for (int am = 0; am < 8; ++am)
#pragma unroll
    for (int r = 0; r < 4; ++r) {
      int row = am * 16 + (lane >> 4) * 4 + r;
      int col = n0 + lr;
      float val = acc[am][r];
      if (bias1) val += bias1[col];
      if (bias2) val += bias2[col];
      outp[(size_t)row * ldc + col] = val;
    }
}

// ---------------------------------------------------------------------------
// K4: per-b scores -> mask -> softmax -> attn_out, ctx -> xcat[:,1024:3072]
__global__ __launch_bounds__(256) void k_attn(
    const float* __restrict__ wa_s,            // [128][1024] (has ba+bUa)
    const float* __restrict__ v,               // [1024]
    const unsigned short* __restrict__ ua_e,   // [8192][1024] bf16
    const unsigned short* __restrict__ enc_b,  // [8192][2048] bf16
    const int* __restrict__ mask,              // [128][64]
    float* __restrict__ attn_out,              // [128][64]
    unsigned short* __restrict__ xcat) {
  __shared__ float s_wa[1024], s_v[1024], s_sc[64], s_w[64];
  const int b = blockIdx.x, tid = threadIdx.x, wave = tid >> 6, lane = tid & 63;
  for (int i = tid; i < 1024; i += 256) { s_wa[i] = wa_s[b * 1024 + i]; s_v[i] = v[i]; }
  __syncthreads();
  for (int l = wave; l < 64; l += 4) {
    const unsigned short* row = ua_e + (size_t)(b * 64 + l) * 1024;
    float p = 0.f;
    for (int h = lane; h < 1024; h += 64)
      p += s_v[h] * tanhf(s_wa[h] + bf16_to_f32(row[h]));
#pragma unroll
    for (int off = 32; off; off >>= 1) p += __shfl_down(p, off);
    if (lane == 0) s_sc[l] = p;
  }
  __syncthreads();
  if (tid < 64) {
    float sc = (mask[b * 64 + tid] == 0) ? -1e9f : s_sc[tid];
    float m = sc;
#pragma unroll
    for (int off = 32; off; off >>= 1) m = fmaxf(m, __shfl_xor(m, off));
    float e = expf(sc - m);
    float s = e;
#pragma unroll
    for (int off = 32; off; off >>= 1) s += __shfl_xor(s, off);
    float w = e / s;
    s_w[tid] = w;
    attn_out[b * 64 + tid] = w;
  }
  __syncthreads();
  float acc[8] = {};
  const unsigned short* eb = enc_b + (size_t)b * 64 * 2048;
  for (int l = 0; l < 64; ++l) {
    float wl = s_w[l];
#pragma unroll
    for (int j = 0; j < 8; ++j)
      acc[j] += wl * bf16_to_f32(eb[l * 2048 + tid + j * 256]);
  }
#pragma unroll
  for (int j = 0; j < 8; ++j)
    xcat[(size_t)b * 4096 + 1024 + tid + j * 256] = f32_to_bf16_rne(acc[j]);
}

// ---------------------------------------------------------------------------
// K6: sum 4 gate partials + biases, LSTM pointwise, emit h1/c1 + h1 bf16
__global__ void k_lstm(const float* __restrict__ gp,  // [4][128][4096]
                       const float* __restrict__ c0,
                       const float* __restrict__ b_ih, const float* __restrict__ b_hh,
                       float* __restrict__ h1_out, float* __restrict__ c1_out,
                       unsigned short* __restrict__ h1b) {
  int idx = blockIdx.x * blockDim.x + threadIdx.x;
  if (idx >= 128 * 1024) return;
  int b = idx >> 10, h = idx & 1023;
  float g4[4];
#pragma unroll
  for (int g = 0; g < 4; ++g) {
    float s = b_ih[g * 1024 + h] + b_hh[g * 1024 + h];
#pragma unroll
    for (int sp = 0; sp < 4; ++sp)
      s += gp[((size_t)sp * 128 + b) * 4096 + g * 1024 + h];
    g4[g] = s;
  }
  float ig = 1.f / (1.f + expf(-g4[0]));
  float fg = 1.f / (1.f + expf(-g4[1]));
  float gg = tanhf(g4[2]);
  float og = 1.f / (1.f + expf(-g4[3]));
  float c1 = fg * c0[idx] + ig * gg;
  float h1 = og * tanhf(c1);
  c1_out[idx] = c1;
  h1_out[idx] = h1;
  h1b[idx] = f32_to_bf16_rne(h1);
}

// ---------------------------------------------------------------------------
// K8: log_softmax over V=32000 per row
__global__ __launch_bounds__(256) void k_logsoftmax(const float* __restrict__ logits,
                                                    float* __restrict__ out) {
  const int b = blockIdx.x, tid = threadIdx.x;
  const float* row = logits + (size_t)b * 32000;
  __shared__ float red[4];
  __shared__ float red2[4];
  float m = -1e30f;
  for (int i = tid; i < 32000; i += 256) m = fmaxf(m, row[i]);
#pragma unroll
  for (int off = 32; off; off >>= 1) m = fmaxf(m, __shfl_xor(m, off));
  if ((tid & 63) == 0) red[tid >> 6] = m;
  __syncthreads();
  m = fmaxf(fmaxf(red[0], red[1]), fmaxf(red[2], red[3]));
  float s = 0.f;
  for (int i = tid; i < 32000; i += 256) s += expf(row[i] - m);
#pragma unroll
  for (int off = 32; off; off >>= 1) s += __shfl_xor(s, off);
  if ((tid & 63) == 0) red2[tid >> 6] = s;
  __syncthreads();
  s = red2[0] + red2[1] + red2[2] + red2[3];
  float lse = m + logf(s);
  for (int i = tid; i < 32000; i += 256) out[(size_t)b * 32000 + i] = row[i] - lse;
}

// ---------------------------------------------------------------------------
extern "C" void kernel_launch(void* const* d_in, const int* in_sizes, int n_in,
                              void* d_out, int out_size, void* d_ws, size_t ws_size,
                              hipStream_t stream) {
  const int*   ids   = (const int*)  d_in[0];
  const float* h0    = (const float*)d_in[1];
  const float* c0    = (const float*)d_in[2];
  const float* enc   = (const float*)d_in[3];
  const int*   mask  = (const int*)  d_in[4];
  const float* emb   = (const float*)d_in[5];
  const float* Wa    = (const float*)d_in[6];
  const float* ba    = (const float*)d_in[7];
  const float* Ua    = (const float*)d_in[8];
  const float* bUa   = (const float*)d_in[9];
  const float* vv    = (const float*)d_in[10];
  const float* W_ih  = (const float*)d_in[11];
  const float* W_hh  = (const float*)d_in[12];
  const float* b_ih  = (const float*)d_in[13];
  const float* b_hh  = (const float*)d_in[14];
  const float* W_out = (const float*)d_in[15];
  const float* b_out = (const float*)d_in[16];

  char* ws = (char*)d_ws;
  unsigned short* enc_b = (unsigned short*)(ws + 0);          // 33,554,432 B
  unsigned short* Ua_b  = (unsigned short*)(ws + 33554432);   //  4,194,304 B
  unsigned short* uae   = (unsigned short*)(ws + 37748736);   // 16,777,216 B
  float*          wa_s  = (float*)(ws + 54525952);            //    524,288 B
  unsigned short* xcat  = (unsigned short*)(ws + 55050240);   //  1,048,576 B
  unsigned short* h1b   = (unsigned short*)(ws + 56098816);   //    262,144 B
  float*          logits = (float*)(ws + 0);                  // alias enc_b (dead after k_attn)
  float*          gpart  = (float*)(ws + 37748736);           // alias uae   (dead after k_attn)

  float* out      = (float*)d_out;
  float* out_logp = out;                      // [128][32000]
  float* out_h1   = out + 4096000;            // [128][1024]
  float* out_c1   = out + 4096000 + 131072;   // [128][1024]
  float* out_attn = out + 4096000 + 262144;   // [128][64]

  // K1: conversions + gather
  k_prep<<<2048, 256, 0, stream>>>(enc, Ua, h0, emb, ids, enc_b, Ua_b, xcat);
  // K2: wa_s = h0 @ Wa.T + ba + bUa   (A = h0 bf16 living at xcat[:,3072:])
  k_gemm_smallM<<<dim3(16, 1), 256, 0, stream>>>(
      xcat + 3072, 4096, Wa, 1024, 1024, nullptr, 0, ba, bUa, wa_s, 1024, 1024, 1024);
  // K3: ua_e = enc @ Ua.T   (bf16 out)
  k_gemm_uae<<<dim3(8, 64), 256, 0, stream>>>(enc_b, Ua_b, uae);
  // K4: scores/softmax/ctx
  k_attn<<<128, 256, 0, stream>>>(wa_s, vv, uae, enc_b, mask, out_attn, xcat);
  // K5: gates partials = xcat @ [W_ih|W_hh]^T, K-split 4
  k_gemm_smallM<<<dim3(64, 4), 256, 0, stream>>>(
      xcat, 4096, W_ih, 3072, 3072, W_hh, 1024, nullptr, nullptr, gpart, 4096, 4096, 1024);
  // K6: LSTM pointwise
  k_lstm<<<512, 256, 0, stream>>>(gpart, c0, b_ih, b_hh, out_h1, out_c1, h1b);
  // K7: logits = h1 @ W_out.T + b_out
  k_gemm_smallM<<<dim3(500, 1), 256, 0, stream>>>(
      h1b, 1024, W_out, 1024, 1024, nullptr, 0, b_out, nullptr, logits, 32000, 1024, 1024);
  // K8: log_softmax -> d_out
  k_logsoftmax<<<128, 256, 0, stream>>>(logits, out_logp);
}